// Round 1
// baseline (490.975 us; speedup 1.0000x reference)
//
#include <hip/hip_runtime.h>
#include <hip/hip_bf16.h>

typedef __attribute__((ext_vector_type(4))) float floatx4;
typedef __attribute__((ext_vector_type(8))) short shortx8;

#define NB   16
#define CIN  256
#define COUT 256
#define KW   3
#define LL   4096
#define NR   5
#define QK   768    // CIN*KW
#define NP   65536  // NB*LL

// ---------------- K0a: transpose x (B,Cin,L) fp32 -> xt (B,L,Cin) bf16 ----------------
__global__ void k_transpose(const float* __restrict__ x, __hip_bfloat16* __restrict__ xt) {
    __shared__ float t[64][65];
    int l0 = blockIdx.x * 64, c0 = blockIdx.y * 64, b = blockIdx.z;
    int tid = threadIdx.x;
    int lx = tid & 63, ry = tid >> 6;  // 4 rows per pass
    #pragma unroll
    for (int i = 0; i < 16; ++i) {
        int cin = i * 4 + ry;
        t[lx][cin] = x[((size_t)(b * CIN + c0 + cin)) * LL + l0 + lx];
    }
    __syncthreads();
    #pragma unroll
    for (int i = 0; i < 16; ++i) {
        int lr = i * 4 + ry;
        xt[((size_t)(b * LL + l0 + lr)) * CIN + c0 + lx] = __float2bfloat16(t[lr][lx]);
    }
}

// ---------------- K0b: weights -> bf16, reorder q' = k*256 + cin ----------------
__global__ void k_wprep(const float* __restrict__ bk, __hip_bfloat16* __restrict__ wb) {
    int i = blockIdx.x * 256 + threadIdx.x;
    if (i >= NR * COUT * QK) return;
    int q = i % QK, oo = i / QK;
    int k = q >> 8, cin = q & 255;
    wb[i] = __float2bfloat16(bk[oo * QK + cin * 3 + k]);
}

// ---------------- K1: controller -> fr (P,5) fp32 ----------------
__global__ void k_fr(const float* __restrict__ x, const float* __restrict__ cw,
                     const float* __restrict__ cb, float* __restrict__ fr) {
    __shared__ float cws[QK * NR];      // 15360 B
    __shared__ float xsh[16][260];      // 16640 B
    int p0 = blockIdx.x * 256;
    int b = p0 >> 12, l0 = p0 & (LL - 1);
    int t = threadIdx.x;
    for (int i = t; i < QK * NR; i += 256) cws[i] = cw[i];
    float lg[NR];
    #pragma unroll
    for (int n = 0; n < NR; ++n) lg[n] = cb[n];
    for (int c0 = 0; c0 < CIN; c0 += 16) {
        __syncthreads();
        for (int i = t; i < 16 * 258; i += 256) {
            int r = i / 258, c = i % 258;
            int gl = l0 - 2 + c;
            xsh[r][c] = (gl >= 0) ? x[((size_t)(b * CIN + c0 + r)) * LL + gl] : 0.f;
        }
        __syncthreads();
        #pragma unroll 4
        for (int r = 0; r < 16; ++r) {
            float x0 = xsh[r][t + 0], x1 = xsh[r][t + 1], x2 = xsh[r][t + 2];
            const float* w = &cws[(c0 + r) * 3 * NR];
            #pragma unroll
            for (int n = 0; n < NR; ++n)
                lg[n] += x0 * w[n] + x1 * w[NR + n] + x2 * w[2 * NR + n];
        }
    }
    float m = lg[0];
    #pragma unroll
    for (int n = 1; n < NR; ++n) m = fmaxf(m, lg[n]);
    float e[NR], s = 0.f;
    #pragma unroll
    for (int n = 0; n < NR; ++n) { e[n] = __expf(lg[n] - m); s += e[n]; }
    float inv = 1.f / s;
    #pragma unroll
    for (int n = 0; n < NR; ++n) fr[(size_t)(p0 + t) * NR + n] = e[n] * inv;
}

// ---------------- K2: fused 5-rule conv + fr-weighted mixture ----------------
// Block tile: Mt=64 (o), Nt=128 (positions). 4 waves in 2x2, wave tile 32x64.
// x-tile staged in LDS in l-major order, cin-halved (two phases) to stay <64KB LDS.
// A-frags (weights) read direct from global (2MB total -> L2 resident).
__global__ __launch_bounds__(256, 2)
void k_conv(const __hip_bfloat16* __restrict__ xt, const __hip_bfloat16* __restrict__ wb,
            const float* __restrict__ fr, const float* __restrict__ bias,
            float* __restrict__ out) {
    __shared__ __align__(16) short xs[130 * 136];  // 35360 B, pad 128->136 (bank stride 4)
    __shared__ float frs[128 * NR];                // 2560 B
    __shared__ float bs[NR * 64];                  // 1280 B

    int p0 = blockIdx.x * 128;
    int o0 = blockIdx.y * 64;
    int b = p0 >> 12, l0 = p0 & (LL - 1);
    int tid = threadIdx.x;
    int lane = tid & 63, wid = tid >> 6;
    int wm = wid >> 1, wn = wid & 1;       // wave grid 2(M) x 2(N)
    int quad = lane >> 4, l16 = lane & 15;

    const __hip_bfloat16* xb = xt + (size_t)b * (LL * CIN);

    // fr tile + bias tile
    for (int i = tid; i < 128 * NR; i += 256) frs[i] = fr[(size_t)p0 * NR + i];
    for (int i = tid; i < NR * 64; i += 256) {
        int n = i >> 6, oo = i & 63;
        bs[i] = bias[n * COUT + o0 + oo];
    }

    floatx4 acc[NR][2][4];
    #pragma unroll
    for (int r = 0; r < NR; ++r)
        #pragma unroll
        for (int mf = 0; mf < 2; ++mf)
            #pragma unroll
            for (int nf = 0; nf < 4; ++nf)
                acc[r][mf][nf] = (floatx4){0.f, 0.f, 0.f, 0.f};

    const shortx8* wv = (const shortx8*)wb;
    int obase_row = o0 + wm * 32 + l16;
    // precompute weight row bases (in shortx8 units): (r*256+o)*768/8 = (r*256+o)*96
    int widx[NR][2];
    #pragma unroll
    for (int r = 0; r < NR; ++r)
        #pragma unroll
        for (int mf = 0; mf < 2; ++mf)
            widx[r][mf] = (r * COUT + obase_row + mf * 16) * 96;

    int rr = tid >> 4, cc = (tid & 15) * 8;
    for (int h = 0; h < 2; ++h) {
        __syncthreads();  // also protects xs reuse between phases
        // stage half x-tile: rows l0-2 .. l0+127, cins [h*128, h*128+128)
        for (int it = 0; it < 9; ++it) {
            int r = it * 16 + rr;
            if (r < 130) {
                int gl = l0 - 2 + r;
                uint4 v = make_uint4(0u, 0u, 0u, 0u);
                if (gl >= 0) v = *(const uint4*)(xb + (size_t)gl * CIN + h * 128 + cc);
                *(uint4*)(&xs[r * 136 + cc]) = v;
            }
        }
        __syncthreads();

        for (int khat = 0; khat < 3; ++khat) {
            for (int cs = 0; cs < 128; cs += 32) {
                shortx8 bfrag[4];
                #pragma unroll
                for (int nf = 0; nf < 4; ++nf) {
                    int row = wn * 64 + nf * 16 + l16 + khat;
                    bfrag[nf] = *(const shortx8*)(&xs[row * 136 + cs + quad * 8]);
                }
                int qoff = (khat * 256 + h * 128 + cs) >> 3;  // + quad below
                #pragma unroll
                for (int r = 0; r < NR; ++r) {
                    shortx8 afrag[2];
                    #pragma unroll
                    for (int mf = 0; mf < 2; ++mf)
                        afrag[mf] = wv[widx[r][mf] + qoff + quad];
                    #pragma unroll
                    for (int mf = 0; mf < 2; ++mf)
                        #pragma unroll
                        for (int nf = 0; nf < 4; ++nf)
                            acc[r][mf][nf] = __builtin_amdgcn_mfma_f32_16x16x32_bf16(
                                afrag[mf], bfrag[nf], acc[r][mf][nf], 0, 0, 0);
                }
            }
        }
    }

    // epilogue: out[b,o,l] = sum_r frs[col][r] * (acc_r + bias[r][o])
    #pragma unroll
    for (int mf = 0; mf < 2; ++mf) {
        int olocal = wm * 32 + mf * 16 + quad * 4;
        #pragma unroll
        for (int nf = 0; nf < 4; ++nf) {
            int colp = wn * 64 + nf * 16 + l16;
            float f0 = frs[colp * NR + 0], f1 = frs[colp * NR + 1], f2 = frs[colp * NR + 2],
                  f3 = frs[colp * NR + 3], f4 = frs[colp * NR + 4];
            #pragma unroll
            for (int j = 0; j < 4; ++j) {
                int ol = olocal + j;
                float v = f0 * (acc[0][mf][nf][j] + bs[0 * 64 + ol])
                        + f1 * (acc[1][mf][nf][j] + bs[1 * 64 + ol])
                        + f2 * (acc[2][mf][nf][j] + bs[2 * 64 + ol])
                        + f3 * (acc[3][mf][nf][j] + bs[3 * 64 + ol])
                        + f4 * (acc[4][mf][nf][j] + bs[4 * 64 + ol]);
                out[((size_t)(b * COUT + o0 + ol)) * LL + l0 + colp] = v;
            }
        }
    }
}

extern "C" void kernel_launch(void* const* d_in, const int* in_sizes, int n_in,
                              void* d_out, int out_size, void* d_ws, size_t ws_size,
                              hipStream_t stream) {
    const float* x  = (const float*)d_in[0];
    const float* bk = (const float*)d_in[1];
    const float* bb = (const float*)d_in[2];
    const float* cw = (const float*)d_in[3];
    const float* cb = (const float*)d_in[4];
    float* out = (float*)d_out;

    char* ws = (char*)d_ws;
    __hip_bfloat16* xt = (__hip_bfloat16*)ws;                         // 33,554,432 B
    __hip_bfloat16* wb = (__hip_bfloat16*)(ws + 33554432);            //  1,966,080 B
    float*          fr = (float*)(ws + 33554432 + 1966080);           //  1,310,720 B

    k_transpose<<<dim3(LL / 64, CIN / 64, NB), dim3(256), 0, stream>>>(x, xt);
    k_wprep<<<dim3((NR * COUT * QK + 255) / 256), dim3(256), 0, stream>>>(bk, wb);
    k_fr<<<dim3(NP / 256), dim3(256), 0, stream>>>(x, cw, cb, fr);
    k_conv<<<dim3(NP / 128, COUT / 64), dim3(256), 0, stream>>>(xt, wb, fr, bb, out);
}

// Round 2
// 446.385 us; speedup vs baseline: 1.0999x; 1.0999x over previous
//
#include <hip/hip_runtime.h>
#include <hip/hip_bf16.h>

typedef __attribute__((ext_vector_type(4))) float floatx4;
typedef __attribute__((ext_vector_type(8))) short shortx8;

#define NB   16
#define CIN  256
#define COUT 256
#define KW   3
#define LL   4096
#define NR   5
#define QK   768    // CIN*KW
#define NP   65536  // NB*LL

static __device__ __forceinline__ unsigned short bf16bits(float f) {
    __hip_bfloat16 h = __float2bfloat16(f);
    return __builtin_bit_cast(unsigned short, h);
}

// ---------------- K0a: transpose x (B,Cin,L) fp32 -> xt (B,L,Cin) bf16 ----------------
// float4 reads (1KB/wave-instr), ushort4 writes (512B/wave-instr)
__global__ void k_transpose(const float* __restrict__ x, __hip_bfloat16* __restrict__ xt) {
    __shared__ float t[64][65];
    int l0 = blockIdx.x * 64, c0 = blockIdx.y * 64, b = blockIdx.z;
    int tid = threadIdx.x;
    int r16 = tid >> 4, q16 = tid & 15;
    #pragma unroll
    for (int pass = 0; pass < 4; ++pass) {
        int cin = pass * 16 + r16;
        float4 v = *(const float4*)&x[((size_t)(b * CIN + c0 + cin)) * LL + l0 + q16 * 4];
        t[q16 * 4 + 0][cin] = v.x;
        t[q16 * 4 + 1][cin] = v.y;
        t[q16 * 4 + 2][cin] = v.z;
        t[q16 * 4 + 3][cin] = v.w;
    }
    __syncthreads();
    #pragma unroll
    for (int pass = 0; pass < 4; ++pass) {
        int lr = pass * 16 + r16;
        int c4 = q16 * 4;
        ushort4 u;
        u.x = bf16bits(t[lr][c4 + 0]);
        u.y = bf16bits(t[lr][c4 + 1]);
        u.z = bf16bits(t[lr][c4 + 2]);
        u.w = bf16bits(t[lr][c4 + 3]);
        *(ushort4*)&xt[((size_t)(b * LL + l0 + lr)) * CIN + c0 + c4] = u;
    }
}

// ---------------- K0b: weights -> bf16, M-order m = (o>>4)*80 + r*16 + (o&15), q' = k*256+cin ----------------
__global__ void k_wprep(const float* __restrict__ bk, __hip_bfloat16* __restrict__ wb) {
    int i = blockIdx.x * 256 + threadIdx.x;
    if (i >= NR * COUT * QK) return;
    int m = i / QK, q = i % QK;
    int o = (m / 80) * 16 + (m & 15);
    int r = (m % 80) / 16;
    int k = q >> 8, cin = q & 255;
    wb[i] = __float2bfloat16(bk[((r * COUT + o) * CIN + cin) * KW + k]);
}

// ---------------- K1: controller -> fr (P,5) fp32. 64 pos/block, waves split Cin ----------------
__global__ void k_fr(const float* __restrict__ x, const float* __restrict__ cw,
                     const float* __restrict__ cb, float* __restrict__ fr) {
    __shared__ float xsh[128][68];     // 34816 B
    __shared__ float cws[QK * NR];     // 15360 B
    __shared__ float part[4][64][NR];  // 5120 B
    int p0 = blockIdx.x * 64;
    int b = p0 >> 12, l0 = p0 & (LL - 1);
    int tid = threadIdx.x, lane = tid & 63, wid = tid >> 6;
    for (int i = tid; i < QK * NR; i += 256) cws[i] = cw[i];
    float lg[NR] = {0.f, 0.f, 0.f, 0.f, 0.f};
    for (int ch = 0; ch < 2; ++ch) {
        __syncthreads();
        // stage cins [ch*128, ch*128+128), cols l0-4 .. l0+63
        for (int i = tid; i < 128 * 17; i += 256) {
            int cl = i / 17, c4 = (i % 17) * 4;
            int gl = l0 - 4 + c4;
            float4 v = make_float4(0.f, 0.f, 0.f, 0.f);
            if (gl >= 0) v = *(const float4*)&x[((size_t)(b * CIN + ch * 128 + cl)) * LL + gl];
            *(float4*)&xsh[cl][c4] = v;
        }
        __syncthreads();
        #pragma unroll 8
        for (int r = 0; r < 32; ++r) {
            int cl = wid * 32 + r;
            int cg = ch * 128 + cl;
            float x0 = xsh[cl][lane + 2], x1 = xsh[cl][lane + 3], x2 = xsh[cl][lane + 4];
            const float* w = &cws[cg * 3 * NR];
            #pragma unroll
            for (int n = 0; n < NR; ++n)
                lg[n] += x0 * w[n] + x1 * w[NR + n] + x2 * w[2 * NR + n];
        }
    }
    #pragma unroll
    for (int n = 0; n < NR; ++n) part[wid][lane][n] = lg[n];
    __syncthreads();
    if (tid < 64) {
        float l2[NR];
        #pragma unroll
        for (int n = 0; n < NR; ++n)
            l2[n] = cb[n] + part[0][tid][n] + part[1][tid][n] + part[2][tid][n] + part[3][tid][n];
        float m = l2[0];
        #pragma unroll
        for (int n = 1; n < NR; ++n) m = fmaxf(m, l2[n]);
        float e[NR], s = 0.f;
        #pragma unroll
        for (int n = 0; n < NR; ++n) { e[n] = __expf(l2[n] - m); s += e[n]; }
        float inv = 1.f / s;
        #pragma unroll
        for (int n = 0; n < NR; ++n) fr[(size_t)(p0 + tid) * NR + n] = e[n] * inv;
    }
}

// ---------------- K2: fused 5-rule conv + fr-weighted mixture ----------------
// GEMM M=1280 (rule folded into M: m=(o>>4)*80+r*16+(o&15)), N=65536, K=768.
// Block: M=80, N=256; 4 waves each own full M x 64-pos sub-tile -> 80 accs/lane.
__global__ __launch_bounds__(256, 3)
void k_conv(const __hip_bfloat16* __restrict__ xt, const __hip_bfloat16* __restrict__ wb,
            const float* __restrict__ fr, const float* __restrict__ bias,
            float* __restrict__ out) {
    __shared__ __align__(16) short xs[258 * 72];  // 37152 B, rows padded 64->72 shorts
    __shared__ float frs[256 * NR];               // 5120 B
    __shared__ float bs[80];                      // 320 B

    int p0 = blockIdx.x * 256;
    int m0 = blockIdx.y * 80, o0 = blockIdx.y * 16;
    int b = p0 >> 12, l0 = p0 & (LL - 1);
    int tid = threadIdx.x;
    int lane = tid & 63, wn = tid >> 6;     // waves split N into 4 x 64
    int quad = lane >> 4, l16 = lane & 15;

    const __hip_bfloat16* xb = xt + (size_t)b * (LL * CIN);

    for (int i = tid; i < 256 * NR; i += 256) frs[i] = fr[(size_t)p0 * NR + i];
    if (tid < 80) bs[tid] = bias[(tid >> 4) * COUT + o0 + (tid & 15)];

    floatx4 acc[NR][4];
    #pragma unroll
    for (int mf = 0; mf < NR; ++mf)
        #pragma unroll
        for (int nf = 0; nf < 4; ++nf)
            acc[mf][nf] = (floatx4){0.f, 0.f, 0.f, 0.f};

    const shortx8* wv = (const shortx8*)wb;
    int widx[NR];
    #pragma unroll
    for (int mf = 0; mf < NR; ++mf)
        widx[mf] = (m0 + mf * 16 + l16) * 96;  // *768/8

    int srow = tid >> 3, su = (tid & 7) * 8;
    for (int h = 0; h < 4; ++h) {
        __syncthreads();
        // stage rows l0-2 .. l0+255, cins [h*64, h*64+64)
        #pragma unroll
        for (int pass = 0; pass < 9; ++pass) {
            int r = pass * 32 + srow;
            if (r < 258) {
                int gl = l0 - 2 + r;
                uint4 v = make_uint4(0u, 0u, 0u, 0u);
                if (gl >= 0) v = *(const uint4*)(xb + (size_t)gl * CIN + h * 64 + su);
                *(uint4*)&xs[r * 72 + su] = v;
            }
        }
        __syncthreads();
        for (int khat = 0; khat < 3; ++khat) {
            #pragma unroll
            for (int csi = 0; csi < 2; ++csi) {
                int cs = csi * 32;
                shortx8 bfrag[4];
                #pragma unroll
                for (int nf = 0; nf < 4; ++nf)
                    bfrag[nf] = *(const shortx8*)&xs[(wn * 64 + nf * 16 + l16 + khat) * 72 + cs + quad * 8];
                int qoff = (khat * 256 + h * 64 + cs) >> 3;
                shortx8 afrag[NR];
                #pragma unroll
                for (int mf = 0; mf < NR; ++mf)
                    afrag[mf] = wv[widx[mf] + qoff + quad];
                #pragma unroll
                for (int mf = 0; mf < NR; ++mf)
                    #pragma unroll
                    for (int nf = 0; nf < 4; ++nf)
                        acc[mf][nf] = __builtin_amdgcn_mfma_f32_16x16x32_bf16(
                            afrag[mf], bfrag[nf], acc[mf][nf], 0, 0, 0);
            }
        }
    }

    // epilogue: out[b, o0+olo, l0+colp] = sum_r frs[colp][r]*(acc[r][..] + bias)
    #pragma unroll
    for (int nf = 0; nf < 4; ++nf) {
        int colp = wn * 64 + nf * 16 + l16;
        float f0 = frs[colp * NR + 0], f1 = frs[colp * NR + 1], f2 = frs[colp * NR + 2],
              f3 = frs[colp * NR + 3], f4 = frs[colp * NR + 4];
        #pragma unroll
        for (int j = 0; j < 4; ++j) {
            int olo = quad * 4 + j;
            float v = f0 * (acc[0][nf][j] + bs[0 * 16 + olo])
                    + f1 * (acc[1][nf][j] + bs[1 * 16 + olo])
                    + f2 * (acc[2][nf][j] + bs[2 * 16 + olo])
                    + f3 * (acc[3][nf][j] + bs[3 * 16 + olo])
                    + f4 * (acc[4][nf][j] + bs[4 * 16 + olo]);
            out[((size_t)(b * COUT + o0 + olo)) * LL + l0 + colp] = v;
        }
    }
}

extern "C" void kernel_launch(void* const* d_in, const int* in_sizes, int n_in,
                              void* d_out, int out_size, void* d_ws, size_t ws_size,
                              hipStream_t stream) {
    const float* x  = (const float*)d_in[0];
    const float* bk = (const float*)d_in[1];
    const float* bb = (const float*)d_in[2];
    const float* cw = (const float*)d_in[3];
    const float* cb = (const float*)d_in[4];
    float* out = (float*)d_out;

    char* ws = (char*)d_ws;
    __hip_bfloat16* xt = (__hip_bfloat16*)ws;                         // 33,554,432 B
    __hip_bfloat16* wb = (__hip_bfloat16*)(ws + 33554432);            //  1,966,080 B
    float*          fr = (float*)(ws + 33554432 + 1966080);           //  1,310,720 B

    k_transpose<<<dim3(LL / 64, CIN / 64, NB), dim3(256), 0, stream>>>(x, xt);
    k_wprep<<<dim3((NR * COUT * QK + 255) / 256), dim3(256), 0, stream>>>(bk, wb);
    k_fr<<<dim3(NP / 64), dim3(256), 0, stream>>>(x, cw, cb, fr);
    k_conv<<<dim3(NP / 256, 16), dim3(256), 0, stream>>>(xt, wb, fr, bb, out);
}

// Round 3
// 361.130 us; speedup vs baseline: 1.3596x; 1.2361x over previous
//
#include <hip/hip_runtime.h>
#include <hip/hip_bf16.h>

typedef __attribute__((ext_vector_type(4))) float floatx4;
typedef __attribute__((ext_vector_type(8))) short shortx8;

#define NB   16
#define CIN  256
#define COUT 256
#define KW   3
#define LL   4096
#define NR   5
#define QK   768    // CIN*KW
#define NP   65536  // NB*LL

static __device__ __forceinline__ unsigned short bf16bits(float f) {
    __hip_bfloat16 h = __float2bfloat16(f);
    return __builtin_bit_cast(unsigned short, h);
}

// ---------------- K0a: transpose x (B,Cin,L) fp32 -> xt (B,L,Cin) bf16 ----------------
__global__ void k_transpose(const float* __restrict__ x, __hip_bfloat16* __restrict__ xt) {
    __shared__ float t[64][65];
    int l0 = blockIdx.x * 64, c0 = blockIdx.y * 64, b = blockIdx.z;
    int tid = threadIdx.x;
    int r16 = tid >> 4, q16 = tid & 15;
    #pragma unroll
    for (int pass = 0; pass < 4; ++pass) {
        int cin = pass * 16 + r16;
        float4 v = *(const float4*)&x[((size_t)(b * CIN + c0 + cin)) * LL + l0 + q16 * 4];
        t[q16 * 4 + 0][cin] = v.x;
        t[q16 * 4 + 1][cin] = v.y;
        t[q16 * 4 + 2][cin] = v.z;
        t[q16 * 4 + 3][cin] = v.w;
    }
    __syncthreads();
    #pragma unroll
    for (int pass = 0; pass < 4; ++pass) {
        int lr = pass * 16 + r16;
        int c4 = q16 * 4;
        ushort4 u;
        u.x = bf16bits(t[lr][c4 + 0]);
        u.y = bf16bits(t[lr][c4 + 1]);
        u.z = bf16bits(t[lr][c4 + 2]);
        u.w = bf16bits(t[lr][c4 + 3]);
        *(ushort4*)&xt[((size_t)(b * LL + l0 + lr)) * CIN + c0 + c4] = u;
    }
}

// ---------------- K0b: weights -> bf16, M-order m = (o>>4)*80 + r*16 + (o&15), q' = k*256+cin ----------------
__global__ void k_wprep(const float* __restrict__ bk, __hip_bfloat16* __restrict__ wb) {
    int i = blockIdx.x * 256 + threadIdx.x;
    if (i >= NR * COUT * QK) return;
    int m = i / QK, q = i % QK;
    int o = (m / 80) * 16 + (m & 15);
    int r = (m % 80) / 16;
    int k = q >> 8, cin = q & 255;
    wb[i] = __float2bfloat16(bk[((r * COUT + o) * CIN + cin) * KW + k]);
}

// ---------------- K1: controller -> fr (P,5) fp32 ----------------
__global__ void k_fr(const float* __restrict__ x, const float* __restrict__ cw,
                     const float* __restrict__ cb, float* __restrict__ fr) {
    __shared__ float xsh[128][68];     // 34816 B
    __shared__ float cws[QK * NR];     // 15360 B
    __shared__ float part[4][64][NR];  // 5120 B
    int p0 = blockIdx.x * 64;
    int b = p0 >> 12, l0 = p0 & (LL - 1);
    int tid = threadIdx.x, lane = tid & 63, wid = tid >> 6;
    for (int i = tid; i < QK * NR; i += 256) cws[i] = cw[i];
    float lg[NR] = {0.f, 0.f, 0.f, 0.f, 0.f};
    for (int ch = 0; ch < 2; ++ch) {
        __syncthreads();
        for (int i = tid; i < 128 * 17; i += 256) {
            int cl = i / 17, c4 = (i % 17) * 4;
            int gl = l0 - 4 + c4;
            float4 v = make_float4(0.f, 0.f, 0.f, 0.f);
            if (gl >= 0) v = *(const float4*)&x[((size_t)(b * CIN + ch * 128 + cl)) * LL + gl];
            *(float4*)&xsh[cl][c4] = v;
        }
        __syncthreads();
        #pragma unroll 8
        for (int r = 0; r < 32; ++r) {
            int cl = wid * 32 + r;
            int cg = ch * 128 + cl;
            float x0 = xsh[cl][lane + 2], x1 = xsh[cl][lane + 3], x2 = xsh[cl][lane + 4];
            const float* w = &cws[cg * 3 * NR];
            #pragma unroll
            for (int n = 0; n < NR; ++n)
                lg[n] += x0 * w[n] + x1 * w[NR + n] + x2 * w[2 * NR + n];
        }
    }
    #pragma unroll
    for (int n = 0; n < NR; ++n) part[wid][lane][n] = lg[n];
    __syncthreads();
    if (tid < 64) {
        float l2[NR];
        #pragma unroll
        for (int n = 0; n < NR; ++n)
            l2[n] = cb[n] + part[0][tid][n] + part[1][tid][n] + part[2][tid][n] + part[3][tid][n];
        float m = l2[0];
        #pragma unroll
        for (int n = 1; n < NR; ++n) m = fmaxf(m, l2[n]);
        float e[NR], s = 0.f;
        #pragma unroll
        for (int n = 0; n < NR; ++n) { e[n] = __expf(l2[n] - m); s += e[n]; }
        float inv = 1.f / s;
        #pragma unroll
        for (int n = 0; n < NR; ++n) fr[(size_t)(p0 + tid) * NR + n] = e[n] * inv;
    }
}

// ---------------- K2: fused conv + mixture, LDS-resident operands, reg-prefetch K-loop ----------------
// GEMM M=1280, N=65536, K=768. Block M=80 x N=256, 4 waves each 80x64.
// 4 K-phases of 64 cins; per phase both x-slice (258x64) and w-slice (80x3x64) live in LDS.
// XOR-swizzled 128B rows: conflict-free writes, 2-way (free) reads.
#define XS_CHUNKS 2064              // 258 rows * 8 chunks
#define WS_CHUNKS 1920              // 240 strips * 8 chunks
#define XS_SHORTS (XS_CHUNKS * 8)   // 16512
__global__ __launch_bounds__(256, 2)
void k_conv(const __hip_bfloat16* __restrict__ xt, const __hip_bfloat16* __restrict__ wb,
            const float* __restrict__ fr, const float* __restrict__ bias,
            float* __restrict__ out) {
    __shared__ __align__(16) short lds[XS_SHORTS + WS_CHUNKS * 8];  // 63744 B
    __shared__ float bs[80];                                        // 320 B

    int g = blockIdx.x;
    int pt = ((g >> 7) << 3) | (g & 7);   // XCD swizzle: same pt -> same XCD (mod-8)
    int y  = (g >> 3) & 15;
    int p0 = pt * 256;
    int m0 = y * 80, o0 = y * 16;
    int b = p0 >> 12, l0 = p0 & (LL - 1);
    int tid = threadIdx.x;
    int lane = tid & 63, wn = tid >> 6;
    int quad = lane >> 4, l16 = lane & 15;

    const __hip_bfloat16* xb = xt + (size_t)b * (LL * CIN);

    if (tid < 80) bs[tid] = bias[(tid >> 4) * COUT + o0 + (tid & 15)];

    // ---- precompute LDS frag read offsets (short indices, phase-invariant) ----
    int boff[3][4], aoff[3][5];
    #pragma unroll
    for (int kh = 0; kh < 3; ++kh) {
        #pragma unroll
        for (int nf = 0; nf < 4; ++nf) {
            int row = wn * 64 + nf * 16 + l16 + kh;
            int phys = quad ^ (row & 7);
            boff[kh][nf] = row * 64 + phys * 8;
        }
        #pragma unroll
        for (int mf = 0; mf < NR; ++mf) {
            int s = kh * 80 + mf * 16 + l16;
            int phys = quad ^ (l16 & 7);
            aoff[kh][mf] = XS_SHORTS + s * 64 + phys * 8;
        }
    }

    floatx4 acc[NR][4];
    #pragma unroll
    for (int mf = 0; mf < NR; ++mf)
        #pragma unroll
        for (int nf = 0; nf < 4; ++nf)
            acc[mf][nf] = (floatx4){0.f, 0.f, 0.f, 0.f};

    // ---- staging helpers (prefetch into regs, write to LDS later) ----
    uint4 sx[9], sw[8];
    auto load_regs = [&](int h) {
        #pragma unroll
        for (int j = 0; j < 9; ++j) {
            int i = tid + j * 256;
            if (j < 8 || i < XS_CHUNKS) {
                int row = i >> 3, cslot = i & 7;
                int cg = cslot ^ (row & 7);
                int gl = l0 - 2 + row;
                int gls = gl < 0 ? 0 : gl;
                uint4 v = *(const uint4*)(xb + (size_t)gls * CIN + h * 64 + cg * 8);
                if (gl < 0) v = make_uint4(0u, 0u, 0u, 0u);
                sx[j] = v;
            }
        }
        #pragma unroll
        for (int j = 0; j < 8; ++j) {
            int i = tid + j * 256;
            if (j < 7 || i < WS_CHUNKS) {
                int s = i >> 3, cslot = i & 7;
                int cg = cslot ^ (s & 7);
                int kh = s / 80, m = s - kh * 80;
                sw[j] = *(const uint4*)(wb + ((m0 + m) * QK + kh * 256 + h * 64 + cg * 8));
            }
        }
    };
    auto store_lds = [&]() {
        #pragma unroll
        for (int j = 0; j < 9; ++j) {
            int i = tid + j * 256;
            if (j < 8 || i < XS_CHUNKS) *(uint4*)&lds[i * 8] = sx[j];
        }
        #pragma unroll
        for (int j = 0; j < 8; ++j) {
            int i = tid + j * 256;
            if (j < 7 || i < WS_CHUNKS) *(uint4*)&lds[XS_SHORTS + i * 8] = sw[j];
        }
    };

    load_regs(0);
    for (int h = 0; h < 4; ++h) {
        store_lds();            // vmcnt-drained loads -> LDS (conflict-free contiguous)
        __syncthreads();
        if (h < 3) load_regs(h + 1);  // in flight during compute
        #pragma unroll
        for (int kh = 0; kh < 3; ++kh) {
            #pragma unroll
            for (int csi = 0; csi < 2; ++csi) {
                int xr = csi * 32;  // chunk phys ^4 -> short index ^32
                shortx8 bfrag[4], afrag[NR];
                #pragma unroll
                for (int nf = 0; nf < 4; ++nf)
                    bfrag[nf] = *(const shortx8*)&lds[boff[kh][nf] ^ xr];
                #pragma unroll
                for (int mf = 0; mf < NR; ++mf)
                    afrag[mf] = *(const shortx8*)&lds[aoff[kh][mf] ^ xr];
                #pragma unroll
                for (int mf = 0; mf < NR; ++mf)
                    #pragma unroll
                    for (int nf = 0; nf < 4; ++nf)
                        acc[mf][nf] = __builtin_amdgcn_mfma_f32_16x16x32_bf16(
                            afrag[mf], bfrag[nf], acc[mf][nf], 0, 0, 0);
            }
        }
        __syncthreads();        // protect LDS overwrite next phase
    }

    // ---- epilogue: out[b, o0+olo, l0+colp] = sum_r fr[p][r]*(acc[r] + bias[r][o]) ----
    #pragma unroll
    for (int nf = 0; nf < 4; ++nf) {
        int colp = wn * 64 + nf * 16 + l16;
        const float* fp = fr + (size_t)(p0 + colp) * NR;
        float f0 = fp[0], f1 = fp[1], f2 = fp[2], f3 = fp[3], f4 = fp[4];
        #pragma unroll
        for (int j = 0; j < 4; ++j) {
            int olo = quad * 4 + j;
            float v = f0 * (acc[0][nf][j] + bs[0 * 16 + olo])
                    + f1 * (acc[1][nf][j] + bs[1 * 16 + olo])
                    + f2 * (acc[2][nf][j] + bs[2 * 16 + olo])
                    + f3 * (acc[3][nf][j] + bs[3 * 16 + olo])
                    + f4 * (acc[4][nf][j] + bs[4 * 16 + olo]);
            out[((size_t)(b * COUT + o0 + olo)) * LL + l0 + colp] = v;
        }
    }
}

extern "C" void kernel_launch(void* const* d_in, const int* in_sizes, int n_in,
                              void* d_out, int out_size, void* d_ws, size_t ws_size,
                              hipStream_t stream) {
    const float* x  = (const float*)d_in[0];
    const float* bk = (const float*)d_in[1];
    const float* bb = (const float*)d_in[2];
    const float* cw = (const float*)d_in[3];
    const float* cb = (const float*)d_in[4];
    float* out = (float*)d_out;

    char* ws = (char*)d_ws;
    __hip_bfloat16* xt = (__hip_bfloat16*)ws;                         // 33,554,432 B
    __hip_bfloat16* wb = (__hip_bfloat16*)(ws + 33554432);            //  1,966,080 B
    float*          fr = (float*)(ws + 33554432 + 1966080);           //  1,310,720 B

    k_transpose<<<dim3(LL / 64, CIN / 64, NB), dim3(256), 0, stream>>>(x, xt);
    k_wprep<<<dim3((NR * COUT * QK + 255) / 256), dim3(256), 0, stream>>>(bk, wb);
    k_fr<<<dim3(NP / 64), dim3(256), 0, stream>>>(x, cw, cb, fr);
    k_conv<<<dim3(NP / 256 * (COUT / 16)), dim3(256), 0, stream>>>(xt, wb, fr, bb, out);
}